// Round 5
// baseline (921.782 us; speedup 1.0000x reference)
//
#include <hip/hip_runtime.h>

// Part_Graph GNN forward on MI355X.
// Inputs: FLOAT32. Output: FLOAT32 (concat):
// [0] xp_new (16,60,3600) | [1] pu_map (16,5,3600) | [2] pl_map (16,3,3600)
// | [3] att_raw (16,16,3600) | [4] ctx_att (16,12,3600)

#define P_TOT 57600
#define RSQEPS 0.99999500003749969f
#define O2 3456000
#define O3 3744000
#define O4 3916800
#define O5 4838400

typedef __attribute__((ext_vector_type(8))) short s8v;
typedef __attribute__((ext_vector_type(4))) float f4v;

__device__ __forceinline__ float bf2f(short s) {
  union { unsigned int i; float f; } u;
  u.i = ((unsigned int)(unsigned short)s) << 16;
  return u.f;
}
__device__ __forceinline__ short f2bf(float f) {
  union { float f; unsigned int i; } u; u.f = f;
  unsigned int r = (u.i + 0x7FFFu + ((u.i >> 16) & 1u)) >> 16;
  return (short)r;
}

// LDS tile index with bank swizzle (same formula for reader and writer).
__device__ __forceinline__ int swz(int m, int c) {
  return m * 256 + (c ^ ((((m >> 3) ^ m) & 7) << 3));
}

// ---------------- K0: MFMA-order weight packing (f32 -> bf16) --------------
#define NW1U 49152
#define NUW  55296
__global__ __launch_bounds__(256) void k0_prep(
    const float* __restrict__ w1, const float* __restrict__ w2,
    short* __restrict__ w1p, short* __restrict__ w2p) {
  int i = blockIdx.x * 256 + threadIdx.x;
  if (i < NW1U) {
    int g = i;
    int lane = g & 63, t1 = g >> 6;
    int kk = t1 & 7, t2 = t1 >> 3;
    int ni = t2 & 3, t3 = t2 >> 2;
    int nblk = t3 & 3, head = t3 >> 2;
    int o = nblk * 64 + ni * 16 + (lane & 15);
    const float* src = w1 + (size_t)head * 65536 + (size_t)o * 256 + kk * 32 + (lane >> 4) * 8;
    short* d = w1p + (size_t)g * 8;
#pragma unroll
    for (int j = 0; j < 8; ++j) d[j] = f2bf(src[j]);
  } else {
    int g = i - NW1U;
    int lane = g & 63, t1 = g >> 6;
    int kk = t1 & 7, t2 = t1 >> 3;
    int f = t2 & 1, head = t2 >> 1;
    int row = f * 16 + (lane & 15);
    short* d = w2p + (size_t)g * 8;
    if (row < 20) {
      const float* src = w2 + (size_t)head * 5120 + (size_t)row * 256 + kk * 32 + (lane >> 4) * 8;
#pragma unroll
      for (int j = 0; j < 8; ++j) d[j] = f2bf(src[j]);
    } else {
#pragma unroll
      for (int j = 0; j < 8; ++j) d[j] = 0;
    }
  }
}

// ---------------- K1: fused proj1 (256->256) + proj2 (256->20), 6 heads ----
__global__ __launch_bounds__(256) void k1_proj(
    const float* __restrict__ xp, const short* __restrict__ w1p,
    const float* __restrict__ g1, const float* __restrict__ b1,
    const short* __restrict__ w2p,
    const float* __restrict__ g2, const float* __restrict__ b2,
    short* __restrict__ ctx) {
  __shared__ short sA[48 * 256];
  __shared__ short sH[48 * 256];
  const int t = threadIdx.x;
  const int p0 = blockIdx.x * 48;         // 48 | 3600 -> never crosses an image
  const int n = p0 / 3600;
  const int hw0 = p0 % 3600;
  const int lane = t & 63;
  const int wid = t >> 6;
  const int l15 = lane & 15;
  const int lg = lane >> 4;

  // stage xp tile (f32 -> bf16): unit u -> (m0=(u%6)*8, c=u/6)
  const float* xpn = xp + (size_t)n * 256 * 3600 + hw0;
#pragma unroll
  for (int it = 0; it < 6; ++it) {
    int u = it * 256 + t;
    int q = u % 6;
    int c = u / 6;
    int m0 = q * 8;
    const float* src = xpn + c * 3600 + m0;
    f4v v0 = *((const f4v*)src);
    f4v v1 = *((const f4v*)(src + 4));
#pragma unroll
    for (int j = 0; j < 4; ++j) {
      sA[swz(m0 + j, c)] = f2bf(v0[j]);
      sA[swz(m0 + 4 + j, c)] = f2bf(v1[j]);
    }
  }
  __syncthreads();

  for (int head = 0; head < 6; ++head) {
    f4v acc[3][4];
#pragma unroll
    for (int mi = 0; mi < 3; ++mi)
#pragma unroll
      for (int ni = 0; ni < 4; ++ni) acc[mi][ni] = (f4v){0.f, 0.f, 0.f, 0.f};
    const int n0 = wid * 64;
    for (int kk = 0; kk < 8; ++kk) {
      s8v a[3], b[4];
#pragma unroll
      for (int mi = 0; mi < 3; ++mi) {
        int m = mi * 16 + l15;
        int c = kk * 32 + lg * 8;
        a[mi] = *((const s8v*)&sA[swz(m, c)]);
      }
#pragma unroll
      for (int ni = 0; ni < 4; ++ni)
        b[ni] = *((const s8v*)(w1p + ((size_t)((((head * 4 + wid) * 4 + ni) * 8 + kk) * 64 + lane)) * 8));
#pragma unroll
      for (int mi = 0; mi < 3; ++mi)
#pragma unroll
        for (int ni = 0; ni < 4; ++ni)
          acc[mi][ni] = __builtin_amdgcn_mfma_f32_16x16x32_bf16(a[mi], b[ni], acc[mi][ni], 0, 0, 0);
    }
    // bn + relu -> sH (bf16).  D layout: row=(lg*4+r), col=l15.
#pragma unroll
    for (int ni = 0; ni < 4; ++ni) {
      int o = n0 + ni * 16 + l15;
      float s = g1[head * 256 + o] * RSQEPS;
      float bb = b1[head * 256 + o];
#pragma unroll
      for (int mi = 0; mi < 3; ++mi)
#pragma unroll
        for (int r = 0; r < 4; ++r) {
          int m = mi * 16 + lg * 4 + r;
          float h = fmaxf(acc[mi][ni][r] * s + bb, 0.f);
          sH[swz(m, o)] = f2bf(h);
        }
    }
    __syncthreads();
    if (wid < 3) {  // GEMM2: wave w owns m-frag w; N=20 padded to 32
      f4v a20 = {0.f, 0.f, 0.f, 0.f}, a21 = {0.f, 0.f, 0.f, 0.f};
      for (int kk = 0; kk < 8; ++kk) {
        int m = wid * 16 + l15;
        int c = kk * 32 + lg * 8;
        s8v av = *((const s8v*)&sH[swz(m, c)]);
        s8v b0 = *((const s8v*)(w2p + ((size_t)(((head * 2 + 0) * 8 + kk) * 64 + lane)) * 8));
        s8v b1v = *((const s8v*)(w2p + ((size_t)(((head * 2 + 1) * 8 + kk) * 64 + lane)) * 8));
        a20 = __builtin_amdgcn_mfma_f32_16x16x32_bf16(av, b0, a20, 0, 0, 0);
        a21 = __builtin_amdgcn_mfma_f32_16x16x32_bf16(av, b1v, a21, 0, 0, 0);
      }
#pragma unroll
      for (int f = 0; f < 2; ++f) {
        int cch = f * 16 + l15;
        if (cch < 20) {
          float s = g2[head * 20 + cch] * RSQEPS;
          float bb = b2[head * 20 + cch];
          short* dst = ctx + (size_t)(head * 20 + cch) * P_TOT + p0;
          f4v& aa = f ? a21 : a20;
#pragma unroll
          for (int r = 0; r < 4; ++r) {
            int m = wid * 16 + lg * 4 + r;
            dst[m] = f2bf(fmaxf(aa[r] * s + bb, 0.f));
          }
        }
      }
    }
    __syncthreads();
  }
}

// ---------------- K2: att_raw / att_soft / ctx_att per pixel ---------------
__global__ __launch_bounds__(256) void k2_att(
    const short* __restrict__ ctx,
    const float* __restrict__ attw, const float* __restrict__ attb,
    const float* __restrict__ ctxw, const float* __restrict__ ctxb,
    float* __restrict__ ws_att, float* __restrict__ out) {
  int p = blockIdx.x * 256 + threadIdx.x;
  int n = p / 3600, hw = p % 3600;
  const int att_off[6] = {0, 2, 5, 8, 11, 14};
#pragma unroll
  for (int i = 0; i < 6; ++i) {
    float fd[10], c0[10];
#pragma unroll
    for (int c = 0; c < 10; ++c) {
      c0[c] = bf2f(ctx[(size_t)(i * 20 + c) * P_TOT + p]);
      fd[c] = bf2f(ctx[(size_t)(i * 20 + 10 + c) * P_TOT + p]);
    }
    const int ci = (i == 0 || i == 5) ? 2 : 3;
    float a[3];
#pragma unroll
    for (int j = 0; j < 3; ++j) {
      if (j < ci) {
        float s = attb[i * 3 + j];
#pragma unroll
        for (int c = 0; c < 10; ++c) s += attw[(i * 3 + j) * 10 + c] * fd[c];
        a[j] = s;
        out[O4 + ((size_t)n * 16 + att_off[i] + j) * 3600 + hw] = s;
      }
    }
    float mx = fmaxf(a[0], a[1]);
    if (ci == 3) mx = fmaxf(mx, a[2]);
    float se = 0.f;
#pragma unroll
    for (int j = 0; j < 3; ++j)
      if (j < ci) { a[j] = __expf(a[j] - mx); se += a[j]; }
    float inv = 1.f / se;
#pragma unroll
    for (int j = 0; j < 3; ++j)
      if (j < ci) ws_att[(size_t)(i * 3 + j) * P_TOT + p] = a[j] * inv;
    float o0 = ctxb[i * 2 + 0];
    float o1 = ctxb[i * 2 + 1];
#pragma unroll
    for (int c = 0; c < 10; ++c) {
      o0 += ctxw[(i * 2 + 0) * 10 + c] * c0[c];
      o1 += ctxw[(i * 2 + 1) * 10 + c] * fd[c];
    }
    out[O5 + ((size_t)n * 12 + i * 2 + 0) * 3600 + hw] = o0;
    out[O5 + ((size_t)n * 12 + i * 2 + 1) * 3600 + hw] = o1;
  }
}

// ---------------- K3: pu/pl maps + softmax gates ---------------------------
__global__ __launch_bounds__(256) void k3_gates(
    const float* __restrict__ xh0, const float* __restrict__ xh1,
    const float* __restrict__ duw, const float* __restrict__ dub,
    const float* __restrict__ dlw, const float* __restrict__ dlb,
    float* __restrict__ ws_pu, float* __restrict__ ws_pl, float* __restrict__ out) {
  int p = blockIdx.x * 256 + threadIdx.x;
  int n = p / 3600, hw = p % 3600;
  float h[10];
#pragma unroll
  for (int c = 0; c < 10; ++c) h[c] = xh0[((size_t)n * 10 + c) * 3600 + hw];
  float a[5];
#pragma unroll
  for (int j = 0; j < 5; ++j) {
    float s = dub[j];
#pragma unroll
    for (int c = 0; c < 10; ++c) s += duw[j * 10 + c] * h[c];
    a[j] = s;
    out[O2 + ((size_t)n * 5 + j) * 3600 + hw] = s;
  }
  float mx = a[0];
#pragma unroll
  for (int j = 1; j < 5; ++j) mx = fmaxf(mx, a[j]);
  float se = 0.f;
#pragma unroll
  for (int j = 0; j < 5; ++j) { a[j] = __expf(a[j] - mx); se += a[j]; }
  float inv = 1.f / se;
#pragma unroll
  for (int j = 0; j < 5; ++j) ws_pu[(size_t)j * P_TOT + p] = a[j] * inv;

#pragma unroll
  for (int c = 0; c < 10; ++c) h[c] = xh1[((size_t)n * 10 + c) * 3600 + hw];
  float b3[3];
#pragma unroll
  for (int j = 0; j < 3; ++j) {
    float s = dlb[j];
#pragma unroll
    for (int c = 0; c < 10; ++c) s += dlw[j * 10 + c] * h[c];
    b3[j] = s;
    out[O3 + ((size_t)n * 3 + j) * 3600 + hw] = s;
  }
  mx = fmaxf(fmaxf(b3[0], b3[1]), b3[2]);
  se = 0.f;
#pragma unroll
  for (int j = 0; j < 3; ++j) { b3[j] = __expf(b3[j] - mx); se += b3[j]; }
  inv = 1.f / se;
#pragma unroll
  for (int j = 0; j < 3; ++j) ws_pl[(size_t)j * P_TOT + p] = b3[j] * inv;
}

// ---------------- K4a: decoder + edge messages -> ws_msg -------------------
static __device__ const int INC_N[6] = {1, 2, 2, 2, 2, 1};
static __device__ const int INC_U[6][2] = {{1, 0}, {0, 2}, {1, 3}, {2, 4}, {3, 5}, {4, 0}};
static __device__ const int INC_K[6][2] = {{1, 0}, {1, 1}, {2, 1}, {2, 1}, {2, 1}, {2, 0}};

// LDS layout (floats): 0: c1w[3][20][20] | 1200: c1s[3][20] | 1260: c1b[3][20]
// | 1320: c2w[3][10][20] | 1920: c2s[3][10] | 1950: c2b[3][10]  (total 1980)
__device__ __forceinline__ void block2_f(const float* __restrict__ in20, int s,
                                         const float* __restrict__ W,
                                         float* __restrict__ out10) {
  float h[20];
#pragma unroll
  for (int o = 0; o < 20; ++o) {
    float acc = 0.f;
#pragma unroll
    for (int c = 0; c < 20; ++c) acc += W[(s * 20 + o) * 20 + c] * in20[c];
    h[o] = fmaxf(acc * W[1200 + s * 20 + o] + W[1260 + s * 20 + o], 0.f);
  }
#pragma unroll
  for (int o = 0; o < 10; ++o) {
    float acc = 0.f;
#pragma unroll
    for (int c = 0; c < 20; ++c) acc += W[1320 + (s * 10 + o) * 20 + c] * h[c];
    out10[o] = fmaxf(acc * W[1920 + s * 10 + o] + W[1950 + s * 10 + o], 0.f);
  }
}

__global__ __launch_bounds__(256, 4) void k4a_msg(
    const float* __restrict__ xh0, const float* __restrict__ xh1,
    const float* __restrict__ xp0, const float* __restrict__ xp1,
    const float* __restrict__ xp2, const float* __restrict__ xp3,
    const float* __restrict__ xp4, const float* __restrict__ xp5,
    const float* __restrict__ ws_pu, const float* __restrict__ ws_pl,
    const float* __restrict__ ws_att, const short* __restrict__ ctx,
    const float* __restrict__ c1wg, const float* __restrict__ c1gg, const float* __restrict__ c1bg,
    const float* __restrict__ c2wg, const float* __restrict__ c2gg, const float* __restrict__ c2bg,
    float* __restrict__ ws_msg) {
  __shared__ float W[1980];
  const int t = threadIdx.x;
  const int node = blockIdx.y;
  for (int u = t; u < 1980; u += 256) {
    float v;
    if (u < 1200) v = c1wg[u];
    else if (u < 1260) v = c1gg[u - 1200] * RSQEPS;
    else if (u < 1320) v = c1bg[u - 1260];
    else if (u < 1920) v = c2wg[u - 1320];
    else if (u < 1950) v = c2gg[u - 1920] * RSQEPS;
    else v = c2bg[u - 1950];
    W[u] = v;
  }
  __syncthreads();
  int p = blockIdx.x * 256 + t;
  int n = p / 3600, hw = p % 3600;
  const float* xhp = (node < 4) ? xh0 : xh1;
  const float* xpl = node == 0 ? xp0 : node == 1 ? xp1 : node == 2 ? xp2
                   : node == 3 ? xp3 : node == 4 ? xp4 : xp5;
  float xpi[10];
#pragma unroll
  for (int c = 0; c < 10; ++c) xpi[c] = xpl[((size_t)n * 10 + c) * 3600 + hw];
  float attg = (node < 4) ? ws_pu[(size_t)(node + 1) * P_TOT + p]
                          : ws_pl[(size_t)(node - 3) * P_TOT + p];
  float in20[20], msg[10], tmp[10];
#pragma unroll
  for (int c = 0; c < 10; ++c) {
    in20[c] = xhp[((size_t)n * 10 + c) * 3600 + hw] * attg;
    in20[10 + c] = xpi[c];
  }
  block2_f(in20, (node < 4) ? 0 : 1, W, msg);
  const int ne = INC_N[node];
  for (int e = 0; e < ne; ++e) {
    int uu = INC_U[node][e], kk = INC_K[node][e];
    float av = ws_att[(size_t)(uu * 3 + kk) * P_TOT + p];
#pragma unroll
    for (int c = 0; c < 10; ++c) {
      in20[c] = av * bf2f(ctx[(size_t)(uu * 20 + 10 + c) * P_TOT + p]);
      in20[10 + c] = xpi[c];
    }
    block2_f(in20, 2, W, tmp);
#pragma unroll
    for (int c = 0; c < 10; ++c) msg[c] += tmp[c];
  }
#pragma unroll
  for (int c = 0; c < 10; ++c)
    ws_msg[(size_t)(node * 10 + c) * P_TOT + p] = msg[c];
}

// ---------------- K4b: GRU per (pixel, node) -------------------------------
// LDS layout (floats): 0: gw[20][20] | 400: gb[20] | 420: cw[10][20] | 620: cb[10]
__global__ __launch_bounds__(256, 4) void k4b_gru(
    const float* __restrict__ xp0, const float* __restrict__ xp1,
    const float* __restrict__ xp2, const float* __restrict__ xp3,
    const float* __restrict__ xp4, const float* __restrict__ xp5,
    const float* __restrict__ ws_msg,
    const float* __restrict__ gwg, const float* __restrict__ gbg,
    const float* __restrict__ cwg, const float* __restrict__ cbg,
    float* __restrict__ out) {
  __shared__ float W[630];
  const int t = threadIdx.x;
  const int node = blockIdx.y;
  for (int u = t; u < 630; u += 256) {
    float v;
    if (u < 400) v = gwg[node * 400 + u];
    else if (u < 420) v = gbg[node * 20 + (u - 400)];
    else if (u < 620) v = cwg[node * 200 + (u - 420)];
    else v = cbg[node * 10 + (u - 620)];
    W[u] = v;
  }
  __syncthreads();
  int p = blockIdx.x * 256 + t;
  int n = p / 3600, hw = p % 3600;
  const float* xpl = node == 0 ? xp0 : node == 1 ? xp1 : node == 2 ? xp2
                   : node == 3 ? xp3 : node == 4 ? xp4 : xp5;
  float xpi[10], msg[10];
#pragma unroll
  for (int c = 0; c < 10; ++c) {
    xpi[c] = xpl[((size_t)n * 10 + c) * 3600 + hw];
    msg[c] = ws_msg[(size_t)(node * 10 + c) * P_TOT + p];
  }
  float g20[20];
#pragma unroll
  for (int o = 0; o < 20; ++o) {
    float acc = W[400 + o];
#pragma unroll
    for (int c = 0; c < 10; ++c)
      acc += W[o * 20 + c] * msg[c] + W[o * 20 + 10 + c] * xpi[c];
    g20[o] = acc;
  }
  float ci20[20];
#pragma unroll
  for (int c = 0; c < 10; ++c) {
    float r = 1.f / (1.f + __expf(-g20[c]));
    ci20[c] = msg[c];
    ci20[10 + c] = r * xpi[c];
  }
#pragma unroll
  for (int o = 0; o < 10; ++o) {
    float acc = W[620 + o];
#pragma unroll
    for (int c = 0; c < 20; ++c) acc += W[420 + o * 20 + c] * ci20[c];
    float cd = tanhf(acc);
    float z = 1.f / (1.f + __expf(-g20[10 + o]));
    float res = (1.f - z) * xpi[o] + z * cd;
    out[((size_t)n * 60 + node * 10 + o) * 3600 + hw] = res;
  }
}

// ---------------- launcher -------------------------------------------------
extern "C" void kernel_launch(void* const* d_in, const int* in_sizes, int n_in,
                              void* d_out, int out_size, void* d_ws, size_t ws_size,
                              hipStream_t stream) {
  const float* xh0 = (const float*)d_in[1];
  const float* xh1 = (const float*)d_in[2];
  const float* xp0 = (const float*)d_in[3];
  const float* xp1 = (const float*)d_in[4];
  const float* xp2 = (const float*)d_in[5];
  const float* xp3 = (const float*)d_in[6];
  const float* xp4 = (const float*)d_in[7];
  const float* xp5 = (const float*)d_in[8];
  const float* xp  = (const float*)d_in[9];
  const float* p1w = (const float*)d_in[10];
  const float* p1g = (const float*)d_in[11];
  const float* p1b = (const float*)d_in[12];
  const float* p2w = (const float*)d_in[13];
  const float* p2g = (const float*)d_in[14];
  const float* p2b = (const float*)d_in[15];
  const float* attw = (const float*)d_in[16];
  const float* attb = (const float*)d_in[17];
  const float* ctxw = (const float*)d_in[18];
  const float* ctxb = (const float*)d_in[19];
  const float* duw = (const float*)d_in[20];
  const float* dub = (const float*)d_in[21];
  const float* dlw = (const float*)d_in[22];
  const float* dlb = (const float*)d_in[23];
  const float* c1w = (const float*)d_in[24];
  const float* c1g = (const float*)d_in[25];
  const float* c1b = (const float*)d_in[26];
  const float* c2w = (const float*)d_in[27];
  const float* c2g = (const float*)d_in[28];
  const float* c2b = (const float*)d_in[29];
  const float* gw  = (const float*)d_in[30];
  const float* gb  = (const float*)d_in[31];
  const float* cw  = (const float*)d_in[32];
  const float* cb  = (const float*)d_in[33];

  // Workspace layout (bytes) — total 34,523,136 B (~33 MB):
  char* wsb = (char*)d_ws;
  short* w1p   = (short*)(wsb);              //    786,432 B
  short* w2p   = (short*)(wsb + 786432);     //     98,304 B
  short* ctxb2 = (short*)(wsb + 884736);     // 13,824,000 B (bf16 ctx [120][57600])
  float* ws_att = (float*)(wsb + 14708736);  //  4,147,200 B
  float* ws_pu  = (float*)(wsb + 18855936);  //  1,152,000 B
  float* ws_pl  = (float*)(wsb + 20007936);  //    691,200 B
  float* ws_msg = (float*)(wsb + 20699136);  // 13,824,000 B (f32 msg [60][57600])
  float* out = (float*)d_out;

  k0_prep<<<216, 256, 0, stream>>>(p1w, p2w, w1p, w2p);
  k1_proj<<<1200, 256, 0, stream>>>(xp, w1p, p1g, p1b, w2p, p2g, p2b, ctxb2);
  k2_att<<<225, 256, 0, stream>>>(ctxb2, attw, attb, ctxw, ctxb, ws_att, out);
  k3_gates<<<225, 256, 0, stream>>>(xh0, xh1, duw, dub, dlw, dlb, ws_pu, ws_pl, out);
  k4a_msg<<<dim3(225, 6), 256, 0, stream>>>(xh0, xh1, xp0, xp1, xp2, xp3, xp4, xp5,
      ws_pu, ws_pl, ws_att, ctxb2, c1w, c1g, c1b, c2w, c2g, c2b, ws_msg);
  k4b_gru<<<dim3(225, 6), 256, 0, stream>>>(xp0, xp1, xp2, xp3, xp4, xp5,
      ws_msg, gw, gb, cw, cb, out);
}

// Round 6
// 332.820 us; speedup vs baseline: 2.7696x; 2.7696x over previous
//
#include <hip/hip_runtime.h>

// Part_Graph GNN forward on MI355X.
// Inputs: FLOAT32. Output: FLOAT32 (concat):
// [0] xp_new (16,60,3600) | [1] pu_map (16,5,3600) | [2] pl_map (16,3,3600)
// | [3] att_raw (16,16,3600) | [4] ctx_att (16,12,3600)

#define P_TOT 57600
#define RSQEPS 0.99999500003749969f
#define O2 3456000
#define O3 3744000
#define O4 3916800
#define O5 4838400

typedef __attribute__((ext_vector_type(8))) short s8v;
typedef __attribute__((ext_vector_type(4))) float f4v;

__device__ __forceinline__ float bf2f(short s) {
  union { unsigned int i; float f; } u;
  u.i = ((unsigned int)(unsigned short)s) << 16;
  return u.f;
}
__device__ __forceinline__ short f2bf(float f) {
  union { float f; unsigned int i; } u; u.f = f;
  unsigned int r = (u.i + 0x7FFFu + ((u.i >> 16) & 1u)) >> 16;
  return (short)r;
}

// LDS tile index with bank swizzle (same formula for reader and writer).
__device__ __forceinline__ int swz(int m, int c) {
  return m * 256 + (c ^ ((((m >> 3) ^ m) & 7) << 3));
}

// ---------------- K0: MFMA-order weight packing (f32 -> bf16) --------------
#define NW1U 49152
#define NUW  55296
__global__ __launch_bounds__(256) void k0_prep(
    const float* __restrict__ w1, const float* __restrict__ w2,
    short* __restrict__ w1p, short* __restrict__ w2p) {
  int i = blockIdx.x * 256 + threadIdx.x;
  if (i < NW1U) {
    int g = i;
    int lane = g & 63, t1 = g >> 6;
    int kk = t1 & 7, t2 = t1 >> 3;
    int ni = t2 & 3, t3 = t2 >> 2;
    int nblk = t3 & 3, head = t3 >> 2;
    int o = nblk * 64 + ni * 16 + (lane & 15);
    const float* src = w1 + (size_t)head * 65536 + (size_t)o * 256 + kk * 32 + (lane >> 4) * 8;
    short* d = w1p + (size_t)g * 8;
#pragma unroll
    for (int j = 0; j < 8; ++j) d[j] = f2bf(src[j]);
  } else {
    int g = i - NW1U;
    int lane = g & 63, t1 = g >> 6;
    int kk = t1 & 7, t2 = t1 >> 3;
    int f = t2 & 1, head = t2 >> 1;
    int row = f * 16 + (lane & 15);
    short* d = w2p + (size_t)g * 8;
    if (row < 20) {
      const float* src = w2 + (size_t)head * 5120 + (size_t)row * 256 + kk * 32 + (lane >> 4) * 8;
#pragma unroll
      for (int j = 0; j < 8; ++j) d[j] = f2bf(src[j]);
    } else {
#pragma unroll
      for (int j = 0; j < 8; ++j) d[j] = 0;
    }
  }
}

// ---------------- K1: fused proj1 (256->256) + proj2 (256->20), 6 heads ----
__global__ __launch_bounds__(256) void k1_proj(
    const float* __restrict__ xp, const short* __restrict__ w1p,
    const float* __restrict__ g1, const float* __restrict__ b1,
    const short* __restrict__ w2p,
    const float* __restrict__ g2, const float* __restrict__ b2,
    short* __restrict__ ctx) {
  __shared__ short sA[48 * 256];
  __shared__ short sH[48 * 256];
  const int t = threadIdx.x;
  const int p0 = blockIdx.x * 48;         // 48 | 3600 -> never crosses an image
  const int n = p0 / 3600;
  const int hw0 = p0 % 3600;
  const int lane = t & 63;
  const int wid = t >> 6;
  const int l15 = lane & 15;
  const int lg = lane >> 4;

  // stage xp tile (f32 -> bf16): unit u -> (m0=(u%6)*8, c=u/6)
  const float* xpn = xp + (size_t)n * 256 * 3600 + hw0;
#pragma unroll
  for (int it = 0; it < 6; ++it) {
    int u = it * 256 + t;
    int q = u % 6;
    int c = u / 6;
    int m0 = q * 8;
    const float* src = xpn + c * 3600 + m0;
    f4v v0 = *((const f4v*)src);
    f4v v1 = *((const f4v*)(src + 4));
#pragma unroll
    for (int j = 0; j < 4; ++j) {
      sA[swz(m0 + j, c)] = f2bf(v0[j]);
      sA[swz(m0 + 4 + j, c)] = f2bf(v1[j]);
    }
  }
  __syncthreads();

  for (int head = 0; head < 6; ++head) {
    f4v acc[3][4];
#pragma unroll
    for (int mi = 0; mi < 3; ++mi)
#pragma unroll
      for (int ni = 0; ni < 4; ++ni) acc[mi][ni] = (f4v){0.f, 0.f, 0.f, 0.f};
    const int n0 = wid * 64;
    for (int kk = 0; kk < 8; ++kk) {
      s8v a[3], b[4];
#pragma unroll
      for (int mi = 0; mi < 3; ++mi) {
        int m = mi * 16 + l15;
        int c = kk * 32 + lg * 8;
        a[mi] = *((const s8v*)&sA[swz(m, c)]);
      }
#pragma unroll
      for (int ni = 0; ni < 4; ++ni)
        b[ni] = *((const s8v*)(w1p + ((size_t)((((head * 4 + wid) * 4 + ni) * 8 + kk) * 64 + lane)) * 8));
#pragma unroll
      for (int mi = 0; mi < 3; ++mi)
#pragma unroll
        for (int ni = 0; ni < 4; ++ni)
          acc[mi][ni] = __builtin_amdgcn_mfma_f32_16x16x32_bf16(a[mi], b[ni], acc[mi][ni], 0, 0, 0);
    }
    // bn + relu -> sH (bf16).  D layout: row=(lg*4+r), col=l15.
#pragma unroll
    for (int ni = 0; ni < 4; ++ni) {
      int o = n0 + ni * 16 + l15;
      float s = g1[head * 256 + o] * RSQEPS;
      float bb = b1[head * 256 + o];
#pragma unroll
      for (int mi = 0; mi < 3; ++mi)
#pragma unroll
        for (int r = 0; r < 4; ++r) {
          int m = mi * 16 + lg * 4 + r;
          float h = fmaxf(acc[mi][ni][r] * s + bb, 0.f);
          sH[swz(m, o)] = f2bf(h);
        }
    }
    __syncthreads();
    if (wid < 3) {  // GEMM2: wave w owns m-frag w; N=20 padded to 32
      f4v a20 = {0.f, 0.f, 0.f, 0.f}, a21 = {0.f, 0.f, 0.f, 0.f};
      for (int kk = 0; kk < 8; ++kk) {
        int m = wid * 16 + l15;
        int c = kk * 32 + lg * 8;
        s8v av = *((const s8v*)&sH[swz(m, c)]);
        s8v b0 = *((const s8v*)(w2p + ((size_t)(((head * 2 + 0) * 8 + kk) * 64 + lane)) * 8));
        s8v b1v = *((const s8v*)(w2p + ((size_t)(((head * 2 + 1) * 8 + kk) * 64 + lane)) * 8));
        a20 = __builtin_amdgcn_mfma_f32_16x16x32_bf16(av, b0, a20, 0, 0, 0);
        a21 = __builtin_amdgcn_mfma_f32_16x16x32_bf16(av, b1v, a21, 0, 0, 0);
      }
#pragma unroll
      for (int f = 0; f < 2; ++f) {
        int cch = f * 16 + l15;
        if (cch < 20) {
          float s = g2[head * 20 + cch] * RSQEPS;
          float bb = b2[head * 20 + cch];
          short* dst = ctx + (size_t)(head * 20 + cch) * P_TOT + p0;
          f4v& aa = f ? a21 : a20;
#pragma unroll
          for (int r = 0; r < 4; ++r) {
            int m = wid * 16 + lg * 4 + r;
            dst[m] = f2bf(fmaxf(aa[r] * s + bb, 0.f));
          }
        }
      }
    }
    __syncthreads();
  }
}

// ---------------- K2: att_raw / att_soft / ctx_att per pixel ---------------
__global__ __launch_bounds__(256) void k2_att(
    const short* __restrict__ ctx,
    const float* __restrict__ attw, const float* __restrict__ attb,
    const float* __restrict__ ctxw, const float* __restrict__ ctxb,
    float* __restrict__ ws_att, float* __restrict__ out) {
  int p = blockIdx.x * 256 + threadIdx.x;
  int n = p / 3600, hw = p % 3600;
  const int att_off[6] = {0, 2, 5, 8, 11, 14};
#pragma unroll
  for (int i = 0; i < 6; ++i) {
    float fd[10], c0[10];
#pragma unroll
    for (int c = 0; c < 10; ++c) {
      c0[c] = bf2f(ctx[(size_t)(i * 20 + c) * P_TOT + p]);
      fd[c] = bf2f(ctx[(size_t)(i * 20 + 10 + c) * P_TOT + p]);
    }
    const int ci = (i == 0 || i == 5) ? 2 : 3;
    float a[3];
#pragma unroll
    for (int j = 0; j < 3; ++j) {
      if (j < ci) {
        float s = attb[i * 3 + j];
#pragma unroll
        for (int c = 0; c < 10; ++c) s += attw[(i * 3 + j) * 10 + c] * fd[c];
        a[j] = s;
        out[O4 + ((size_t)n * 16 + att_off[i] + j) * 3600 + hw] = s;
      }
    }
    float mx = fmaxf(a[0], a[1]);
    if (ci == 3) mx = fmaxf(mx, a[2]);
    float se = 0.f;
#pragma unroll
    for (int j = 0; j < 3; ++j)
      if (j < ci) { a[j] = __expf(a[j] - mx); se += a[j]; }
    float inv = 1.f / se;
#pragma unroll
    for (int j = 0; j < 3; ++j)
      if (j < ci) ws_att[(size_t)(i * 3 + j) * P_TOT + p] = a[j] * inv;
    float o0 = ctxb[i * 2 + 0];
    float o1 = ctxb[i * 2 + 1];
#pragma unroll
    for (int c = 0; c < 10; ++c) {
      o0 += ctxw[(i * 2 + 0) * 10 + c] * c0[c];
      o1 += ctxw[(i * 2 + 1) * 10 + c] * fd[c];
    }
    out[O5 + ((size_t)n * 12 + i * 2 + 0) * 3600 + hw] = o0;
    out[O5 + ((size_t)n * 12 + i * 2 + 1) * 3600 + hw] = o1;
  }
}

// ---------------- K3: pu/pl maps + softmax gates ---------------------------
__global__ __launch_bounds__(256) void k3_gates(
    const float* __restrict__ xh0, const float* __restrict__ xh1,
    const float* __restrict__ duw, const float* __restrict__ dub,
    const float* __restrict__ dlw, const float* __restrict__ dlb,
    float* __restrict__ ws_pu, float* __restrict__ ws_pl, float* __restrict__ out) {
  int p = blockIdx.x * 256 + threadIdx.x;
  int n = p / 3600, hw = p % 3600;
  float h[10];
#pragma unroll
  for (int c = 0; c < 10; ++c) h[c] = xh0[((size_t)n * 10 + c) * 3600 + hw];
  float a[5];
#pragma unroll
  for (int j = 0; j < 5; ++j) {
    float s = dub[j];
#pragma unroll
    for (int c = 0; c < 10; ++c) s += duw[j * 10 + c] * h[c];
    a[j] = s;
    out[O2 + ((size_t)n * 5 + j) * 3600 + hw] = s;
  }
  float mx = a[0];
#pragma unroll
  for (int j = 1; j < 5; ++j) mx = fmaxf(mx, a[j]);
  float se = 0.f;
#pragma unroll
  for (int j = 0; j < 5; ++j) { a[j] = __expf(a[j] - mx); se += a[j]; }
  float inv = 1.f / se;
#pragma unroll
  for (int j = 0; j < 5; ++j) ws_pu[(size_t)j * P_TOT + p] = a[j] * inv;

#pragma unroll
  for (int c = 0; c < 10; ++c) h[c] = xh1[((size_t)n * 10 + c) * 3600 + hw];
  float b3[3];
#pragma unroll
  for (int j = 0; j < 3; ++j) {
    float s = dlb[j];
#pragma unroll
    for (int c = 0; c < 10; ++c) s += dlw[j * 10 + c] * h[c];
    b3[j] = s;
    out[O3 + ((size_t)n * 3 + j) * 3600 + hw] = s;
  }
  mx = fmaxf(fmaxf(b3[0], b3[1]), b3[2]);
  se = 0.f;
#pragma unroll
  for (int j = 0; j < 3; ++j) { b3[j] = __expf(b3[j] - mx); se += b3[j]; }
  inv = 1.f / se;
#pragma unroll
  for (int j = 0; j < 3; ++j) ws_pl[(size_t)j * P_TOT + p] = b3[j] * inv;
}

// ---------------- K4: decoder + edge messages + GRU, one pixel/thread ------
// All weight reads use wave-uniform addresses -> compiler emits s_load and
// v_fmac with an SGPR operand: zero VGPR pressure from weights, no LDS.
static __device__ const int INC_N[6] = {1, 2, 2, 2, 2, 1};
static __device__ const int INC_U[6][2] = {{1, 0}, {0, 2}, {1, 3}, {2, 4}, {3, 5}, {4, 0}};
static __device__ const int INC_K[6][2] = {{1, 0}, {1, 1}, {2, 1}, {2, 1}, {2, 1}, {2, 0}};

template <bool ACCUM>
__device__ __forceinline__ void block2_g(
    const float* __restrict__ w1, const float* __restrict__ g1, const float* __restrict__ b1,
    const float* __restrict__ w2, const float* __restrict__ g2, const float* __restrict__ b2,
    const float* __restrict__ ina, const float* __restrict__ inb,
    float* __restrict__ out10) {
  float h[20];
#pragma unroll
  for (int o = 0; o < 20; ++o) {
    float acc = 0.f;
#pragma unroll
    for (int c = 0; c < 10; ++c)
      acc += w1[o * 20 + c] * ina[c] + w1[o * 20 + 10 + c] * inb[c];
    h[o] = fmaxf(acc * (g1[o] * RSQEPS) + b1[o], 0.f);
  }
#pragma unroll
  for (int o = 0; o < 10; ++o) {
    float acc = 0.f;
#pragma unroll
    for (int c = 0; c < 20; ++c) acc += w2[o * 20 + c] * h[c];
    float v = fmaxf(acc * (g2[o] * RSQEPS) + b2[o], 0.f);
    if (ACCUM) out10[o] += v; else out10[o] = v;
  }
}

__global__ __launch_bounds__(256) void k4_node(
    const float* __restrict__ xh0, const float* __restrict__ xh1,
    const float* __restrict__ xp0, const float* __restrict__ xp1,
    const float* __restrict__ xp2, const float* __restrict__ xp3,
    const float* __restrict__ xp4, const float* __restrict__ xp5,
    const float* __restrict__ ws_pu, const float* __restrict__ ws_pl,
    const float* __restrict__ ws_att, const short* __restrict__ ctx,
    const float* __restrict__ c1w, const float* __restrict__ c1g, const float* __restrict__ c1b,
    const float* __restrict__ c2w, const float* __restrict__ c2g, const float* __restrict__ c2b,
    const float* __restrict__ gw, const float* __restrict__ gb,
    const float* __restrict__ cw, const float* __restrict__ cb,
    float* __restrict__ out) {
  const int t = threadIdx.x;
  const int node = blockIdx.y;
  const int sdec = (node < 4) ? 0 : 1;
  int p = blockIdx.x * 256 + t;
  int n = p / 3600, hw = p % 3600;
  const float* xhp = (node < 4) ? xh0 : xh1;
  const float* xpl = node == 0 ? xp0 : node == 1 ? xp1 : node == 2 ? xp2
                   : node == 3 ? xp3 : node == 4 ? xp4 : xp5;
  float xpi[10];
#pragma unroll
  for (int c = 0; c < 10; ++c) xpi[c] = xpl[((size_t)n * 10 + c) * 3600 + hw];
  float attg = (node < 4) ? ws_pu[(size_t)(node + 1) * P_TOT + p]
                          : ws_pl[(size_t)(node - 3) * P_TOT + p];
  float gated[10], msg[10];
#pragma unroll
  for (int c = 0; c < 10; ++c)
    gated[c] = xhp[((size_t)n * 10 + c) * 3600 + hw] * attg;
  block2_g<false>(c1w + sdec * 400, c1g + sdec * 20, c1b + sdec * 20,
                  c2w + sdec * 200, c2g + sdec * 10, c2b + sdec * 10,
                  gated, xpi, msg);
  const int ne = INC_N[node];
  for (int e = 0; e < ne; ++e) {
    int uu = INC_U[node][e], kk = INC_K[node][e];
    float av = ws_att[(size_t)(uu * 3 + kk) * P_TOT + p];
#pragma unroll
    for (int c = 0; c < 10; ++c)
      gated[c] = av * bf2f(ctx[(size_t)(uu * 20 + 10 + c) * P_TOT + p]);
    block2_g<true>(c1w + 800, c1g + 40, c1b + 40, c2w + 400, c2g + 20, c2b + 20,
                   gated, xpi, msg);
  }
  // GRU
  const float* gwn = gw + node * 400;
  const float* cwn = cw + node * 200;
  float g20[20];
#pragma unroll
  for (int o = 0; o < 20; ++o) {
    float acc = gb[node * 20 + o];
#pragma unroll
    for (int c = 0; c < 10; ++c)
      acc += gwn[o * 20 + c] * msg[c] + gwn[o * 20 + 10 + c] * xpi[c];
    g20[o] = acc;
  }
  float rh[10];
#pragma unroll
  for (int c = 0; c < 10; ++c) {
    float r = 1.f / (1.f + __expf(-g20[c]));
    rh[c] = r * xpi[c];
  }
#pragma unroll
  for (int o = 0; o < 10; ++o) {
    float acc = cb[node * 10 + o];
#pragma unroll
    for (int c = 0; c < 10; ++c)
      acc += cwn[o * 20 + c] * msg[c] + cwn[o * 20 + 10 + c] * rh[c];
    // tanh(x) = 1 - 2/(exp(2x)+1), inline, saturating
    float ex = __expf(2.f * acc);
    float cd = 1.f - 2.f / (ex + 1.f);
    float z = 1.f / (1.f + __expf(-g20[10 + o]));
    float res = (1.f - z) * xpi[o] + z * cd;
    out[((size_t)n * 60 + node * 10 + o) * 3600 + hw] = res;
  }
}

// ---------------- launcher -------------------------------------------------
extern "C" void kernel_launch(void* const* d_in, const int* in_sizes, int n_in,
                              void* d_out, int out_size, void* d_ws, size_t ws_size,
                              hipStream_t stream) {
  const float* xh0 = (const float*)d_in[1];
  const float* xh1 = (const float*)d_in[2];
  const float* xp0 = (const float*)d_in[3];
  const float* xp1 = (const float*)d_in[4];
  const float* xp2 = (const float*)d_in[5];
  const float* xp3 = (const float*)d_in[6];
  const float* xp4 = (const float*)d_in[7];
  const float* xp5 = (const float*)d_in[8];
  const float* xp  = (const float*)d_in[9];
  const float* p1w = (const float*)d_in[10];
  const float* p1g = (const float*)d_in[11];
  const float* p1b = (const float*)d_in[12];
  const float* p2w = (const float*)d_in[13];
  const float* p2g = (const float*)d_in[14];
  const float* p2b = (const float*)d_in[15];
  const float* attw = (const float*)d_in[16];
  const float* attb = (const float*)d_in[17];
  const float* ctxw = (const float*)d_in[18];
  const float* ctxb = (const float*)d_in[19];
  const float* duw = (const float*)d_in[20];
  const float* dub = (const float*)d_in[21];
  const float* dlw = (const float*)d_in[22];
  const float* dlb = (const float*)d_in[23];
  const float* c1w = (const float*)d_in[24];
  const float* c1g = (const float*)d_in[25];
  const float* c1b = (const float*)d_in[26];
  const float* c2w = (const float*)d_in[27];
  const float* c2g = (const float*)d_in[28];
  const float* c2b = (const float*)d_in[29];
  const float* gw  = (const float*)d_in[30];
  const float* gb  = (const float*)d_in[31];
  const float* cw  = (const float*)d_in[32];
  const float* cb  = (const float*)d_in[33];

  // Workspace layout (bytes) — total 20,699,136 B (~19.7 MB):
  char* wsb = (char*)d_ws;
  short* w1p   = (short*)(wsb);              //    786,432 B
  short* w2p   = (short*)(wsb + 786432);     //     98,304 B
  short* ctxb2 = (short*)(wsb + 884736);     // 13,824,000 B (bf16 ctx [120][57600])
  float* ws_att = (float*)(wsb + 14708736);  //  4,147,200 B
  float* ws_pu  = (float*)(wsb + 18855936);  //  1,152,000 B
  float* ws_pl  = (float*)(wsb + 20007936);  //    691,200 B
  float* out = (float*)d_out;

  k0_prep<<<216, 256, 0, stream>>>(p1w, p2w, w1p, w2p);
  k1_proj<<<1200, 256, 0, stream>>>(xp, w1p, p1g, p1b, w2p, p2g, p2b, ctxb2);
  k2_att<<<225, 256, 0, stream>>>(ctxb2, attw, attb, ctxw, ctxb, ws_att, out);
  k3_gates<<<225, 256, 0, stream>>>(xh0, xh1, duw, dub, dlw, dlb, ws_pu, ws_pl, out);
  k4_node<<<dim3(225, 6), 256, 0, stream>>>(xh0, xh1, xp0, xp1, xp2, xp3, xp4, xp5,
      ws_pu, ws_pl, ws_att, ctxb2,
      c1w, c1g, c1b, c2w, c2g, c2b, gw, gb, cw, cb, out);
}